// Round 18
// baseline (60.794 us; speedup 1.0000x reference)
//
#include <hip/hip_runtime.h>
#include <math.h>

#define EPSF 1e-7f
#define BETA_F 0.08838834764831845f

typedef __attribute__((ext_vector_type(8))) short bf8_t;   // 8 x bf16 bits
typedef __attribute__((ext_vector_type(4))) float f32x4;

// ---------------- workspace layout (float offsets), all dedicated, no aliasing ----------------
#define WS_KT    0          // 2048
#define WS_VTM   2048       // 2048
#define WS_LV    4096       // 2048
#define WS_KHI   6144       // 131072 -> 137216
#define WS_KLO   137216     // -> 268288
#define WS_VHI   268288     // -> 399360
#define WS_VLO   399360     // -> 530432
#define WS_VTHI  530432     // -> 661504
#define WS_VTLO  661504     // -> 792576
#define WS_PART  792576     // 1081344 -> end 1873920 f = 7.5 MB

__device__ __forceinline__ float wave_sum(float v) {
#pragma unroll
  for (int off = 32; off > 0; off >>= 1) v += __shfl_xor(v, off);
  return v;
}
__device__ __forceinline__ unsigned short f2bf(float x) {
  unsigned int u = __float_as_uint(x);
  u += 0x7FFFu + ((u >> 16) & 1u);
  return (unsigned short)(u >> 16);
}
__device__ __forceinline__ float bf2f(unsigned short h) {
  return __uint_as_float(((unsigned int)h) << 16);
}
__device__ __forceinline__ void split3(float x, unsigned short& s0, unsigned short& s1,
                                       unsigned short& s2) {
  s0 = f2bf(x);
  float r1 = x - bf2f(s0);
  s1 = f2bf(r1);
  s2 = f2bf(r1 - bf2f(s1));
}
__device__ __forceinline__ bf8_t ld8(const unsigned short* p) {
  return __builtin_bit_cast(bf8_t, *(const uint4*)p);
}
__device__ __forceinline__ f32x4 mfma16(bf8_t a, bf8_t b, f32x4 c) {
  return __builtin_amdgcn_mfma_f32_16x16x32_bf16(a, b, c, 0, 0, 0);
}

// ---------------- dispatch 1: fused prep (R17 verbatim) ----------------
__launch_bounds__(512, 2)
__global__ void prep_kv_w(const float* __restrict__ keys, const float* __restrict__ values,
                          const float* __restrict__ WK, const float* __restrict__ WV,
                          unsigned short* __restrict__ Khi, unsigned short* __restrict__ Klo,
                          float* __restrict__ kt,
                          unsigned short* __restrict__ Vhi, unsigned short* __restrict__ Vlo,
                          unsigned short* __restrict__ VThi, unsigned short* __restrict__ VTlo,
                          float* __restrict__ vt, float* __restrict__ lv) {
  int tid = threadIdx.x, wv = tid >> 6, lane = tid & 63;
  int l15 = lane & 15, lh = lane >> 4;
  int b = blockIdx.x;
  bool isK = b < 128;
  int r0 = (b & 127) * 16;
  const float* src = isK ? keys : values;
  int ncol = wv * 16 + l15;

  __shared__ __align__(16) float ldsD[16][132];
  __shared__ __align__(16) unsigned short v1p[3][16][128];
  __shared__ __align__(16) float ldsD2[16][132];
  __shared__ __align__(16) float ldsT[128][17];

  f32x4 acc = f32x4{0, 0, 0, 0};
  const float* arow = src + (size_t)(r0 + l15) * 512 + lh * 8;

  float4 pa0[2], pa1[2];
  float wkb[2][8];
  pa0[0] = *(const float4*)(arow);
  pa1[0] = *(const float4*)(arow + 4);
#pragma unroll
  for (int i = 0; i < 8; ++i) wkb[0][i] = WK[(size_t)(lh * 8 + i) * 128 + ncol];
  pa0[1] = *(const float4*)(arow + 32);
  pa1[1] = *(const float4*)(arow + 36);
#pragma unroll
  for (int i = 0; i < 8; ++i) wkb[1][i] = WK[(size_t)(32 + lh * 8 + i) * 128 + ncol];
  __builtin_amdgcn_sched_barrier(0);

#pragma unroll
  for (int ks = 0; ks < 16; ++ks) {
    const int cur = ks & 1;
    float4 a0 = pa0[cur], a1 = pa1[cur];
    float wb[8];
#pragma unroll
    for (int i = 0; i < 8; ++i) wb[i] = wkb[cur][i];
    if (ks < 14) {
      pa0[cur] = *(const float4*)(arow + (ks + 2) * 32);
      pa1[cur] = *(const float4*)(arow + (ks + 2) * 32 + 4);
#pragma unroll
      for (int i = 0; i < 8; ++i)
        wkb[cur][i] = WK[(size_t)((ks + 2) * 32 + lh * 8 + i) * 128 + ncol];
    }
    __builtin_amdgcn_sched_barrier(0);
    float av[8] = {a0.x, a0.y, a0.z, a0.w, a1.x, a1.y, a1.z, a1.w};
    bf8_t aa0, aa1, aa2;
#pragma unroll
    for (int i = 0; i < 8; ++i) {
      unsigned short p0, p1, p2;
      split3(av[i], p0, p1, p2);
      aa0[i] = (short)p0; aa1[i] = (short)p1; aa2[i] = (short)p2;
    }
    bf8_t bb0, bb1, bb2;
#pragma unroll
    for (int i = 0; i < 8; ++i) {
      unsigned short p0, p1, p2;
      split3(wb[i], p0, p1, p2);
      bb0[i] = (short)p0; bb1[i] = (short)p1; bb2[i] = (short)p2;
    }
    acc = mfma16(aa0, bb0, acc);
    acc = mfma16(aa0, bb1, acc);
    acc = mfma16(aa1, bb0, acc);
    acc = mfma16(aa0, bb2, acc);
    acc = mfma16(aa1, bb1, acc);
    acc = mfma16(aa2, bb0, acc);
  }
#pragma unroll
  for (int r = 0; r < 4; ++r) ldsD[lh * 4 + r][wv * 16 + l15] = acc[r];
  __syncthreads();

  if (isK) {
    if (tid < 256) {
      int row = tid >> 4, l = tid & 15;
      float a[8];
#pragma unroll
      for (int n = 0; n < 8; ++n) a[n] = ldsD[row][n * 16 + l];
      float s2 = 0.f;
#pragma unroll
      for (int n = 0; n < 8; ++n) s2 += a[n] * a[n];
#pragma unroll
      for (int off = 1; off < 16; off <<= 1) s2 += __shfl_xor(s2, off);
      float nn = sqrtf(s2);
      float f = fminf(3.5f / (nn + EPSF), 1.0f);
      float t = fmaxf(nn * f, EPSF);
      float coef = sinhf(t) / t * f;
      if (l == 0) kt[r0 + row] = coshf(t);
#pragma unroll
      for (int n = 0; n < 8; ++n) {
        float sv = coef * a[n];
        unsigned short h = f2bf(sv);
        Khi[(size_t)(r0 + row) * 128 + n * 16 + l] = h;
        Klo[(size_t)(r0 + row) * 128 + n * 16 + l] = f2bf(sv - bf2f(h));
      }
    }
    return;
  }

  if (tid < 256) {
    int row = tid >> 4, l = tid & 15;
#pragma unroll
    for (int n = 0; n < 8; ++n) {
      unsigned short p0, p1, p2;
      split3(ldsD[row][n * 16 + l], p0, p1, p2);
      v1p[0][row][n * 16 + l] = p0;
      v1p[1][row][n * 16 + l] = p1;
      v1p[2][row][n * 16 + l] = p2;
    }
  }
  __syncthreads();

  f32x4 a2 = f32x4{0, 0, 0, 0};
  float wvb[2][8];
#pragma unroll
  for (int i = 0; i < 8; ++i) wvb[0][i] = WV[(size_t)(lh * 8 + i) * 128 + ncol];
  __builtin_amdgcn_sched_barrier(0);
#pragma unroll
  for (int ks = 0; ks < 4; ++ks) {
    const int cur = ks & 1;
    float wb[8];
#pragma unroll
    for (int i = 0; i < 8; ++i) wb[i] = wvb[cur][i];
    if (ks < 3) {
#pragma unroll
      for (int i = 0; i < 8; ++i)
        wvb[cur ^ 1][i] = WV[(size_t)((ks + 1) * 32 + lh * 8 + i) * 128 + ncol];
    }
    __builtin_amdgcn_sched_barrier(0);
    bf8_t bb0, bb1, bb2;
#pragma unroll
    for (int i = 0; i < 8; ++i) {
      unsigned short p0, p1, p2;
      split3(wb[i], p0, p1, p2);
      bb0[i] = (short)p0; bb1[i] = (short)p1; bb2[i] = (short)p2;
    }
    bf8_t x0 = ld8(&v1p[0][l15][ks * 32 + lh * 8]);
    bf8_t x1 = ld8(&v1p[1][l15][ks * 32 + lh * 8]);
    bf8_t x2 = ld8(&v1p[2][l15][ks * 32 + lh * 8]);
    a2 = mfma16(x0, bb0, a2);
    a2 = mfma16(x0, bb1, a2);
    a2 = mfma16(x1, bb0, a2);
    a2 = mfma16(x0, bb2, a2);
    a2 = mfma16(x1, bb1, a2);
    a2 = mfma16(x2, bb0, a2);
  }
#pragma unroll
  for (int r = 0; r < 4; ++r) ldsD2[lh * 4 + r][wv * 16 + l15] = a2[r];
  __syncthreads();

  if (tid < 256) {
    int row = tid >> 4, l = tid & 15;
    float a[8];
#pragma unroll
    for (int n = 0; n < 8; ++n) a[n] = ldsD2[row][n * 16 + l];
    float s2 = 0.f;
#pragma unroll
    for (int n = 0; n < 8; ++n) s2 += a[n] * a[n];
#pragma unroll
    for (int off = 1; off < 16; off <<= 1) s2 += __shfl_xor(s2, off);
    float nn = sqrtf(s2);
    float f = fminf(3.5f / (nn + EPSF), 1.0f);
    float t = fmaxf(nn * f, EPSF);
    float coef = sinhf(t) / t * f;
    float ch = coshf(t);
    if (l == 0) {
      vt[r0 + row] = ch;
      lv[r0 + row] = coef * coef * s2 - ch * ch;
    }
#pragma unroll
    for (int n = 0; n < 8; ++n) {
      float sv = coef * a[n];
      unsigned short h = f2bf(sv);
      Vhi[(size_t)(r0 + row) * 128 + n * 16 + l] = h;
      Vlo[(size_t)(r0 + row) * 128 + n * 16 + l] = f2bf(sv - bf2f(h));
      ldsT[n * 16 + l][row] = sv;
    }
  }
  __syncthreads();

  if (tid < 128) {
    int d = tid;
    unsigned int wh[8], wl[8];
#pragma unroll
    for (int i = 0; i < 8; ++i) {
      float s0 = ldsT[d][2 * i], s1 = ldsT[d][2 * i + 1];
      unsigned short h0 = f2bf(s0), h1 = f2bf(s1);
      unsigned short g0 = f2bf(s0 - bf2f(h0)), g1 = f2bf(s1 - bf2f(h1));
      wh[i] = (unsigned)h0 | ((unsigned)h1 << 16);
      wl[i] = (unsigned)g0 | ((unsigned)g1 << 16);
    }
    size_t o = (size_t)d * 2048 + r0;
    *(uint4*)(VThi + o) = make_uint4(wh[0], wh[1], wh[2], wh[3]);
    *(uint4*)(VThi + o + 8) = make_uint4(wh[4], wh[5], wh[6], wh[7]);
    *(uint4*)(VTlo + o) = make_uint4(wl[0], wl[1], wl[2], wl[3]);
    *(uint4*)(VTlo + o + 8) = make_uint4(wl[4], wl[5], wl[6], wl[7]);
  }
}

// ---------------- dispatch 2: MFMA pair phase; K/V tile-0/1 loads hoisted above Q-prep ----------------
__launch_bounds__(256, 2)
__global__ void attn_mfma(const float* __restrict__ queries,
                          const unsigned short* __restrict__ Khi, const unsigned short* __restrict__ Klo,
                          const unsigned short* __restrict__ Vhi, const unsigned short* __restrict__ Vlo,
                          const unsigned short* __restrict__ VThi, const unsigned short* __restrict__ VTlo,
                          const float* __restrict__ kt, const float* __restrict__ vt,
                          const float* __restrict__ lv, float* __restrict__ part) {
  int tid = threadIdx.x, wv = tid >> 6, lane = tid & 63;
  int l15 = lane & 15, lh = lane >> 4;
  int qg = blockIdx.x >> 3, sp = blockIdx.x & 7;
  int q0 = qg * 16;
  int j0 = sp * 256 + wv * 64;

  __shared__ __align__(16) unsigned short qtH[16][128];
  __shared__ __align__(16) unsigned short qtL[16][128];
  __shared__ float qtS[16], lqS[16];
  __shared__ __align__(16) unsigned short ghA[4][1024];
  __shared__ __align__(16) unsigned short glA[4][1024];
  __shared__ __align__(16) float mergeO[4][16][132];
  __shared__ float mergeS[4][3][16];

  auto loadT = [&](bf8_t* st, int nn) {
    size_t jrow = (size_t)(j0 + nn * 16 + l15) * 128 + lh * 8;
#pragma unroll
    for (int ks = 0; ks < 4; ++ks) {
      st[ks * 4 + 0] = ld8(Khi + jrow + ks * 32);
      st[ks * 4 + 1] = ld8(Klo + jrow + ks * 32);
      st[ks * 4 + 2] = ld8(Vhi + jrow + ks * 32);
      st[ks * 4 + 3] = ld8(Vlo + jrow + ks * 32);
    }
  };

  // ---- issue K/V tiles 0,1 FIRST: latency hides under the transcendental-heavy Q-prep ----
  bf8_t stA[16], stB[16];
  loadT(stA, 0);
  loadT(stB, 1);
  __builtin_amdgcn_sched_barrier(0);

  // ---- in-block Q prep (R17 verbatim; FP chain identical to prep_q) ----
#pragma unroll
  for (int e = 0; e < 4; ++e) {
    int row = wv * 4 + e;
    int i = q0 + row;
    float2 r = ((const float2*)(queries + (size_t)i * 128))[lane];
    float s2q = wave_sum(r.x * r.x + r.y * r.y);
    float nq = sqrtf(s2q);
    float fq = fminf(3.5f / (nq + EPSF), 1.0f);
    float tq = fmaxf(nq * fq, EPSF);
    float coefq = sinhf(tq) / tq * fq;
    float chq = coshf(tq);
    float x0 = coefq * r.x, x1 = coefq * r.y;
    unsigned short h0 = f2bf(x0), h1 = f2bf(x1);
    qtH[row][2 * lane] = h0;
    qtH[row][2 * lane + 1] = h1;
    unsigned short g0 = f2bf(x0 - bf2f(h0)), g1 = f2bf(x1 - bf2f(h1));
    qtL[row][2 * lane] = g0;
    qtL[row][2 * lane + 1] = g1;
    if (lane == 0) {
      qtS[row] = chq;
      lqS[row] = coefq * coefq * s2q - chq * chq;
    }
  }
  __syncthreads();

  bf8_t qfh[4], qfl[4];
#pragma unroll
  for (int ks = 0; ks < 4; ++ks) {
    qfh[ks] = ld8(&qtH[l15][lh * 8 + ks * 32]);
    qfl[ks] = ld8(&qtL[l15][lh * 8 + ks * 32]);
  }
  float qtr[4], lq2[4];
#pragma unroll
  for (int r = 0; r < 4; ++r) {
    qtr[r] = qtS[lh * 4 + r];
    lq2[r] = 2.0f + lqS[lh * 4 + r];
  }
  float ktj[4], vtj[4], lvj[4];
#pragma unroll
  for (int n = 0; n < 4; ++n) {
    int j = j0 + n * 16 + l15;
    ktj[n] = kt[j]; vtj[n] = vt[j]; lvj[n] = lv[j];
  }

  auto mfmaT = [&](const bf8_t* st, f32x4& s, f32x4& c) {
#pragma unroll
    for (int ks = 0; ks < 4; ++ks) {
      s = mfma16(qfh[ks], st[ks * 4 + 0], s);
      s = mfma16(qfh[ks], st[ks * 4 + 1], s);
      s = mfma16(qfl[ks], st[ks * 4 + 0], s);
      c = mfma16(qfh[ks], st[ks * 4 + 2], c);
      c = mfma16(qfh[ks], st[ks * 4 + 3], c);
      c = mfma16(qfl[ks], st[ks * 4 + 2], c);
    }
  };
  f32x4 sf[4], cf[4];
#pragma unroll
  for (int n = 0; n < 4; ++n) { sf[n] = f32x4{0, 0, 0, 0}; cf[n] = f32x4{0, 0, 0, 0}; }
  mfmaT(stA, sf[0], cf[0]);
  loadT(stA, 2);
  mfmaT(stB, sf[1], cf[1]);
  loadT(stB, 3);
  mfmaT(stA, sf[2], cf[2]);
  mfmaT(stB, sf[3], cf[3]);

  bf8_t vA[16], vB[16];
  auto loadV = [&](bf8_t* st, int jk) {
#pragma unroll
    for (int dn = 0; dn < 8; ++dn) {
      size_t vrow = (size_t)(dn * 16 + l15) * 2048 + j0 + jk * 32 + lh * 8;
      st[dn * 2 + 0] = ld8(VThi + vrow);
      st[dn * 2 + 1] = ld8(VTlo + vrow);
    }
  };
  loadV(vA, 0);

  float lsum[4] = {0, 0, 0, 0}, tcs[4] = {0, 0, 0, 0}, tts[4] = {0, 0, 0, 0};
#pragma unroll
  for (int n = 0; n < 4; ++n) {
#pragma unroll
    for (int r = 0; r < 4; ++r) {
      float sim = sf[n][r] - qtr[r] * ktj[n];
      float c = cf[n][r] - qtr[r] * vtj[n];
      float e = expf(-BETA_F * sim);
      float z = fmaxf(-c, 1.0f + EPSF);
      float dist = acoshf(z);
      float den2 = fmaxf(lvj[n] + lq2[r] * c * c, EPSF);
      float g = e * dist * rsqrtf(den2);
      lsum[r] += e;
      tcs[r] += g * c;
      tts[r] += g * vtj[n];
      unsigned short gh = f2bf(g);
      unsigned short gl = f2bf(g - bf2f(gh));
      int q_ = lh * 4 + r;
      int idx = (q_ * 64 + n * 16 + l15) ^ ((q_ & 7) << 3);
      ghA[wv][idx] = gh;
      glA[wv][idx] = gl;
    }
  }
  loadV(vB, 1);
  asm volatile("s_waitcnt lgkmcnt(0)" ::: "memory");
  __builtin_amdgcn_sched_barrier(0);

  f32x4 accO[8];
#pragma unroll
  for (int dn = 0; dn < 8; ++dn) accO[dn] = f32x4{0, 0, 0, 0};
  {
    int base0 = (l15 * 64 + 0 * 32 + lh * 8) ^ ((l15 & 7) << 3);
    bf8_t ah = ld8(&ghA[wv][base0]);
    bf8_t al = ld8(&glA[wv][base0]);
#pragma unroll
    for (int dn = 0; dn < 8; ++dn) {
      accO[dn] = mfma16(ah, vA[dn * 2 + 0], accO[dn]);
      accO[dn] = mfma16(ah, vA[dn * 2 + 1], accO[dn]);
      accO[dn] = mfma16(al, vA[dn * 2 + 0], accO[dn]);
    }
  }
  {
    int base1 = (l15 * 64 + 1 * 32 + lh * 8) ^ ((l15 & 7) << 3);
    bf8_t ah = ld8(&ghA[wv][base1]);
    bf8_t al = ld8(&glA[wv][base1]);
#pragma unroll
    for (int dn = 0; dn < 8; ++dn) {
      accO[dn] = mfma16(ah, vB[dn * 2 + 0], accO[dn]);
      accO[dn] = mfma16(ah, vB[dn * 2 + 1], accO[dn]);
      accO[dn] = mfma16(al, vB[dn * 2 + 0], accO[dn]);
    }
  }

#pragma unroll
  for (int r = 0; r < 4; ++r) {
#pragma unroll
    for (int off = 1; off < 16; off <<= 1) {
      lsum[r] += __shfl_xor(lsum[r], off);
      tcs[r] += __shfl_xor(tcs[r], off);
      tts[r] += __shfl_xor(tts[r], off);
    }
  }

#pragma unroll
  for (int r = 0; r < 4; ++r) {
    int q_ = lh * 4 + r;
#pragma unroll
    for (int dn = 0; dn < 8; ++dn) mergeO[wv][q_][dn * 16 + l15] = accO[dn][r];
    if (l15 == 0) {
      mergeS[wv][0][q_] = lsum[r];
      mergeS[wv][1][q_] = tcs[r];
      mergeS[wv][2][q_] = tts[r];
    }
  }
  __syncthreads();

#pragma unroll
  for (int e = 0; e < 2; ++e) {
    int t = tid + e * 256;
    int q_ = t >> 5, d0 = (t & 31) * 4;
    float4 s = make_float4(0.f, 0.f, 0.f, 0.f);
#pragma unroll
    for (int w = 0; w < 4; ++w) {
      float4 v = *(const float4*)&mergeO[w][q_][d0];
      s.x += v.x; s.y += v.y; s.z += v.z; s.w += v.w;
    }
    float* P = part + ((size_t)(q0 + q_) * 8 + sp) * 132;
    *(float4*)(P + d0) = s;
  }
  if (tid < 16) {
    int q_ = tid;
    float a = 0, b = 0, cc2 = 0;
#pragma unroll
    for (int w = 0; w < 4; ++w) {
      a += mergeS[w][0][q_];
      b += mergeS[w][1][q_];
      cc2 += mergeS[w][2][q_];
    }
    float* P = part + ((size_t)(q0 + q_) * 8 + sp) * 132;
    P[128] = a; P[129] = b; P[130] = cc2;
  }
}

// ---------------- dispatch 3: merge + epilogue (wave per query, 4 queries/block) ----------------
__global__ void merge_fin(const float* __restrict__ part, const float* __restrict__ queries,
                          float* __restrict__ out) {
  int qi = blockIdx.x * 4 + (threadIdx.x >> 6);
  int lane = threadIdx.x & 63;
  const float* P = part + (size_t)qi * 8 * 132;
  float ox = 0, oy = 0, l = 0, tc = 0, tt = 0;
#pragma unroll
  for (int s = 0; s < 8; ++s) {
    const float* p = P + s * 132;
    float2 o2 = *(const float2*)(p + 2 * lane);
    ox += o2.x; oy += o2.y;
    l += p[128]; tc += p[129]; tt += p[130];
  }
  float2 rq = ((const float2*)(queries + (size_t)qi * 128))[lane];
  float s2q = wave_sum(rq.x * rq.x + rq.y * rq.y);
  float nq = sqrtf(s2q);
  float fq = fminf(3.5f / (nq + EPSF), 1.0f);
  float tq = fmaxf(nq * fq, EPSF);
  float coefq = sinhf(tq) / tq * fq;
  float qtv = coshf(tq);
  float qx = coefq * rq.x, qy = coefq * rq.y;
  float invl = 1.0f / l;
  float Tmx = (ox + tc * qx) * invl;
  float Tmy = (oy + tc * qy) * invl;
  float Tmt = (tt + tc * qtv) * invl;
  float sp2 = wave_sum(Tmx * Tmx + Tmy * Tmy);
  float LT = sp2 - Tmt * Tmt;
  float un = sqrtf(fmaxf(LT, EPSF));
  float ch = coshf(un);
  float shv = sinhf(un) / un;
  float zx = ch * qx + shv * Tmx;
  float zy = ch * qy + shv * Tmy;
  float zt = ch * qtv + shv * Tmt;
  float zn2 = wave_sum(zx * zx + zy * zy);
  float nz = fmaxf(sqrtf(zn2), EPSF);
  float dist = acoshf(fmaxf(zt, 1.0f + EPSF));
  float sc = dist / nz;
  ((float2*)(out + (size_t)qi * 128))[lane] = make_float2(sc * zx, sc * zy);
}

extern "C" void kernel_launch(void* const* d_in, const int* in_sizes, int n_in,
                              void* d_out, int out_size, void* d_ws, size_t ws_size,
                              hipStream_t stream) {
  const float* queries = (const float*)d_in[0];
  const float* keys = (const float*)d_in[1];
  const float* values = (const float*)d_in[2];
  const float* WK = (const float*)d_in[3];
  const float* WV = (const float*)d_in[4];
  float* ws = (float*)d_ws;

  float* kt_ = ws + WS_KT;
  float* vt_ = ws + WS_VTM;
  float* lv_ = ws + WS_LV;
  unsigned short* Khi = (unsigned short*)(ws + WS_KHI);
  unsigned short* Klo = (unsigned short*)(ws + WS_KLO);
  unsigned short* Vhi = (unsigned short*)(ws + WS_VHI);
  unsigned short* Vlo = (unsigned short*)(ws + WS_VLO);
  unsigned short* VThi = (unsigned short*)(ws + WS_VTHI);
  unsigned short* VTlo = (unsigned short*)(ws + WS_VTLO);
  float* part = ws + WS_PART;
  float* out = (float*)d_out;

  prep_kv_w<<<256, 512, 0, stream>>>(keys, values, WK, WV,
                                     Khi, Klo, kt_, Vhi, Vlo, VThi, VTlo, vt_, lv_);
  attn_mfma<<<512, 256, 0, stream>>>(queries, Khi, Klo, Vhi, Vlo, VThi, VTlo,
                                     kt_, vt_, lv_, part);
  merge_fin<<<256, 256, 0, stream>>>(part, queries, out);
}

// Round 19
// 58.378 us; speedup vs baseline: 1.0414x; 1.0414x over previous
//
#include <hip/hip_runtime.h>
#include <math.h>

#define EPSF 1e-7f
#define BETA_F 0.08838834764831845f

typedef __attribute__((ext_vector_type(8))) short bf8_t;   // 8 x bf16 bits
typedef __attribute__((ext_vector_type(4))) float f32x4;

// ---------------- workspace layout (float offsets), all dedicated, no aliasing ----------------
#define WS_KT    0          // 2048
#define WS_VTM   2048       // 2048
#define WS_LV    4096       // 2048
#define WS_KHI   6144       // 131072 -> 137216
#define WS_KLO   137216     // -> 268288
#define WS_VHI   268288     // -> 399360
#define WS_VLO   399360     // -> 530432
#define WS_VTHI  530432     // -> 661504
#define WS_VTLO  661504     // -> 792576
#define WS_PART  792576     // 1081344 -> end 1873920 f = 7.5 MB

__device__ __forceinline__ float wave_sum(float v) {
#pragma unroll
  for (int off = 32; off > 0; off >>= 1) v += __shfl_xor(v, off);
  return v;
}
__device__ __forceinline__ unsigned short f2bf(float x) {
  unsigned int u = __float_as_uint(x);
  u += 0x7FFFu + ((u >> 16) & 1u);
  return (unsigned short)(u >> 16);
}
__device__ __forceinline__ float bf2f(unsigned short h) {
  return __uint_as_float(((unsigned int)h) << 16);
}
__device__ __forceinline__ void split3(float x, unsigned short& s0, unsigned short& s1,
                                       unsigned short& s2) {
  s0 = f2bf(x);
  float r1 = x - bf2f(s0);
  s1 = f2bf(r1);
  s2 = f2bf(r1 - bf2f(s1));
}
__device__ __forceinline__ bf8_t ld8(const unsigned short* p) {
  return __builtin_bit_cast(bf8_t, *(const uint4*)p);
}
__device__ __forceinline__ f32x4 mfma16(bf8_t a, bf8_t b, f32x4 c) {
  return __builtin_amdgcn_mfma_f32_16x16x32_bf16(a, b, c, 0, 0, 0);
}

// ---------------- dispatch 1: fused prep (K/V GEMMs + tangent maps; W converted in-register) ----
// 256 blocks x 512 threads. blocks 0..127: K path; 128..255: V path.
__launch_bounds__(512, 2)
__global__ void prep_kv_w(const float* __restrict__ keys, const float* __restrict__ values,
                          const float* __restrict__ WK, const float* __restrict__ WV,
                          unsigned short* __restrict__ Khi, unsigned short* __restrict__ Klo,
                          float* __restrict__ kt,
                          unsigned short* __restrict__ Vhi, unsigned short* __restrict__ Vlo,
                          unsigned short* __restrict__ VThi, unsigned short* __restrict__ VTlo,
                          float* __restrict__ vt, float* __restrict__ lv) {
  int tid = threadIdx.x, wv = tid >> 6, lane = tid & 63;
  int l15 = lane & 15, lh = lane >> 4;
  int b = blockIdx.x;
  bool isK = b < 128;
  int r0 = (b & 127) * 16;
  const float* src = isK ? keys : values;
  int ncol = wv * 16 + l15;                // B fragment output-column index

  __shared__ __align__(16) float ldsD[16][132];
  __shared__ __align__(16) unsigned short v1p[3][16][128];
  __shared__ __align__(16) float ldsD2[16][132];
  __shared__ __align__(16) float ldsT[128][17];

  // ---- GEMM1: depth-2 A+B staging; B converted in-register; 3-way split, 6-pass ----
  f32x4 acc = f32x4{0, 0, 0, 0};
  const float* arow = src + (size_t)(r0 + l15) * 512 + lh * 8;

  float4 pa0[2], pa1[2];
  float wkb[2][8];
  pa0[0] = *(const float4*)(arow);
  pa1[0] = *(const float4*)(arow + 4);
#pragma unroll
  for (int i = 0; i < 8; ++i) wkb[0][i] = WK[(size_t)(lh * 8 + i) * 128 + ncol];
  pa0[1] = *(const float4*)(arow + 32);
  pa1[1] = *(const float4*)(arow + 36);
#pragma unroll
  for (int i = 0; i < 8; ++i) wkb[1][i] = WK[(size_t)(32 + lh * 8 + i) * 128 + ncol];
  __builtin_amdgcn_sched_barrier(0);

#pragma unroll
  for (int ks = 0; ks < 16; ++ks) {
    const int cur = ks & 1;
    float4 a0 = pa0[cur], a1 = pa1[cur];
    float wb[8];
#pragma unroll
    for (int i = 0; i < 8; ++i) wb[i] = wkb[cur][i];
    if (ks < 14) {
      pa0[cur] = *(const float4*)(arow + (ks + 2) * 32);
      pa1[cur] = *(const float4*)(arow + (ks + 2) * 32 + 4);
#pragma unroll
      for (int i = 0; i < 8; ++i)
        wkb[cur][i] = WK[(size_t)((ks + 2) * 32 + lh * 8 + i) * 128 + ncol];
    }
    __builtin_amdgcn_sched_barrier(0);   // pin prefetch above this iteration's compute
    float av[8] = {a0.x, a0.y, a0.z, a0.w, a1.x, a1.y, a1.z, a1.w};
    bf8_t aa0, aa1, aa2;
#pragma unroll
    for (int i = 0; i < 8; ++i) {
      unsigned short p0, p1, p2;
      split3(av[i], p0, p1, p2);
      aa0[i] = (short)p0; aa1[i] = (short)p1; aa2[i] = (short)p2;
    }
    bf8_t bb0, bb1, bb2;
#pragma unroll
    for (int i = 0; i < 8; ++i) {
      unsigned short p0, p1, p2;
      split3(wb[i], p0, p1, p2);
      bb0[i] = (short)p0; bb1[i] = (short)p1; bb2[i] = (short)p2;
    }
    acc = mfma16(aa0, bb0, acc);
    acc = mfma16(aa0, bb1, acc);
    acc = mfma16(aa1, bb0, acc);
    acc = mfma16(aa0, bb2, acc);
    acc = mfma16(aa1, bb1, acc);
    acc = mfma16(aa2, bb0, acc);
  }
#pragma unroll
  for (int r = 0; r < 4; ++r) ldsD[lh * 4 + r][wv * 16 + l15] = acc[r];
  __syncthreads();

  if (isK) {
    // ---- K tangent epilogue ----
    if (tid < 256) {
      int row = tid >> 4, l = tid & 15;
      float a[8];
#pragma unroll
      for (int n = 0; n < 8; ++n) a[n] = ldsD[row][n * 16 + l];
      float s2 = 0.f;
#pragma unroll
      for (int n = 0; n < 8; ++n) s2 += a[n] * a[n];
#pragma unroll
      for (int off = 1; off < 16; off <<= 1) s2 += __shfl_xor(s2, off);
      float nn = sqrtf(s2);
      float f = fminf(3.5f / (nn + EPSF), 1.0f);
      float t = fmaxf(nn * f, EPSF);
      float coef = sinhf(t) / t * f;
      if (l == 0) kt[r0 + row] = coshf(t);
#pragma unroll
      for (int n = 0; n < 8; ++n) {
        float sv = coef * a[n];
        unsigned short h = f2bf(sv);
        Khi[(size_t)(r0 + row) * 128 + n * 16 + l] = h;
        Klo[(size_t)(r0 + row) * 128 + n * 16 + l] = f2bf(sv - bf2f(h));
      }
    }
    return;
  }

  // ---- V path: V1 tile -> split3 -> LDS planes ----
  if (tid < 256) {
    int row = tid >> 4, l = tid & 15;
#pragma unroll
    for (int n = 0; n < 8; ++n) {
      unsigned short p0, p1, p2;
      split3(ldsD[row][n * 16 + l], p0, p1, p2);
      v1p[0][row][n * 16 + l] = p0;
      v1p[1][row][n * 16 + l] = p1;
      v1p[2][row][n * 16 + l] = p2;
    }
  }
  __syncthreads();

  // ---- GEMM2: B from WV in-register ----
  f32x4 a2 = f32x4{0, 0, 0, 0};
  float wvb[2][8];
#pragma unroll
  for (int i = 0; i < 8; ++i) wvb[0][i] = WV[(size_t)(lh * 8 + i) * 128 + ncol];
  __builtin_amdgcn_sched_barrier(0);
#pragma unroll
  for (int ks = 0; ks < 4; ++ks) {
    const int cur = ks & 1;
    float wb[8];
#pragma unroll
    for (int i = 0; i < 8; ++i) wb[i] = wvb[cur][i];
    if (ks < 3) {
#pragma unroll
      for (int i = 0; i < 8; ++i)
        wvb[cur ^ 1][i] = WV[(size_t)((ks + 1) * 32 + lh * 8 + i) * 128 + ncol];
    }
    __builtin_amdgcn_sched_barrier(0);
    bf8_t bb0, bb1, bb2;
#pragma unroll
    for (int i = 0; i < 8; ++i) {
      unsigned short p0, p1, p2;
      split3(wb[i], p0, p1, p2);
      bb0[i] = (short)p0; bb1[i] = (short)p1; bb2[i] = (short)p2;
    }
    bf8_t x0 = ld8(&v1p[0][l15][ks * 32 + lh * 8]);
    bf8_t x1 = ld8(&v1p[1][l15][ks * 32 + lh * 8]);
    bf8_t x2 = ld8(&v1p[2][l15][ks * 32 + lh * 8]);
    a2 = mfma16(x0, bb0, a2);
    a2 = mfma16(x0, bb1, a2);
    a2 = mfma16(x1, bb0, a2);
    a2 = mfma16(x0, bb2, a2);
    a2 = mfma16(x1, bb1, a2);
    a2 = mfma16(x2, bb0, a2);
  }
#pragma unroll
  for (int r = 0; r < 4; ++r) ldsD2[lh * 4 + r][wv * 16 + l15] = a2[r];
  __syncthreads();

  // ---- V tangent epilogue ----
  if (tid < 256) {
    int row = tid >> 4, l = tid & 15;
    float a[8];
#pragma unroll
    for (int n = 0; n < 8; ++n) a[n] = ldsD2[row][n * 16 + l];
    float s2 = 0.f;
#pragma unroll
    for (int n = 0; n < 8; ++n) s2 += a[n] * a[n];
#pragma unroll
    for (int off = 1; off < 16; off <<= 1) s2 += __shfl_xor(s2, off);
    float nn = sqrtf(s2);
    float f = fminf(3.5f / (nn + EPSF), 1.0f);
    float t = fmaxf(nn * f, EPSF);
    float coef = sinhf(t) / t * f;
    float ch = coshf(t);
    if (l == 0) {
      vt[r0 + row] = ch;
      lv[r0 + row] = coef * coef * s2 - ch * ch;
    }
#pragma unroll
    for (int n = 0; n < 8; ++n) {
      float sv = coef * a[n];
      unsigned short h = f2bf(sv);
      Vhi[(size_t)(r0 + row) * 128 + n * 16 + l] = h;
      Vlo[(size_t)(r0 + row) * 128 + n * 16 + l] = f2bf(sv - bf2f(h));
      ldsT[n * 16 + l][row] = sv;
    }
  }
  __syncthreads();

  // ---- transposed store ----
  if (tid < 128) {
    int d = tid;
    unsigned int wh[8], wl[8];
#pragma unroll
    for (int i = 0; i < 8; ++i) {
      float s0 = ldsT[d][2 * i], s1 = ldsT[d][2 * i + 1];
      unsigned short h0 = f2bf(s0), h1 = f2bf(s1);
      unsigned short g0 = f2bf(s0 - bf2f(h0)), g1 = f2bf(s1 - bf2f(h1));
      wh[i] = (unsigned)h0 | ((unsigned)h1 << 16);
      wl[i] = (unsigned)g0 | ((unsigned)g1 << 16);
    }
    size_t o = (size_t)d * 2048 + r0;
    *(uint4*)(VThi + o) = make_uint4(wh[0], wh[1], wh[2], wh[3]);
    *(uint4*)(VThi + o + 8) = make_uint4(wh[4], wh[5], wh[6], wh[7]);
    *(uint4*)(VTlo + o) = make_uint4(wl[0], wl[1], wl[2], wl[3]);
    *(uint4*)(VTlo + o + 8) = make_uint4(wl[4], wl[5], wl[6], wl[7]);
  }
}

// ---------------- dispatch 2: MFMA pair phase + in-block Q prep ----------------
__launch_bounds__(256, 2)
__global__ void attn_mfma(const float* __restrict__ queries,
                          const unsigned short* __restrict__ Khi, const unsigned short* __restrict__ Klo,
                          const unsigned short* __restrict__ Vhi, const unsigned short* __restrict__ Vlo,
                          const unsigned short* __restrict__ VThi, const unsigned short* __restrict__ VTlo,
                          const float* __restrict__ kt, const float* __restrict__ vt,
                          const float* __restrict__ lv, float* __restrict__ part) {
  int tid = threadIdx.x, wv = tid >> 6, lane = tid & 63;
  int l15 = lane & 15, lh = lane >> 4;
  int qg = blockIdx.x >> 3, sp = blockIdx.x & 7;
  int q0 = qg * 16;
  int j0 = sp * 256 + wv * 64;

  __shared__ __align__(16) unsigned short qtH[16][128];
  __shared__ __align__(16) unsigned short qtL[16][128];
  __shared__ float qtS[16], lqS[16];
  __shared__ __align__(16) unsigned short ghA[4][1024];
  __shared__ __align__(16) unsigned short glA[4][1024];
  __shared__ __align__(16) float mergeO[4][16][132];
  __shared__ float mergeS[4][3][16];

  // ---- in-block Q prep: wave wv computes rows wv*4..+4 (FP chain identical to prep_q) ----
#pragma unroll
  for (int e = 0; e < 4; ++e) {
    int row = wv * 4 + e;
    int i = q0 + row;
    float2 r = ((const float2*)(queries + (size_t)i * 128))[lane];
    float s2q = wave_sum(r.x * r.x + r.y * r.y);
    float nq = sqrtf(s2q);
    float fq = fminf(3.5f / (nq + EPSF), 1.0f);
    float tq = fmaxf(nq * fq, EPSF);
    float coefq = sinhf(tq) / tq * fq;
    float chq = coshf(tq);
    float x0 = coefq * r.x, x1 = coefq * r.y;
    unsigned short h0 = f2bf(x0), h1 = f2bf(x1);
    qtH[row][2 * lane] = h0;
    qtH[row][2 * lane + 1] = h1;
    unsigned short g0 = f2bf(x0 - bf2f(h0)), g1 = f2bf(x1 - bf2f(h1));
    qtL[row][2 * lane] = g0;
    qtL[row][2 * lane + 1] = g1;
    if (lane == 0) {
      qtS[row] = chq;
      lqS[row] = coefq * coefq * s2q - chq * chq;
    }
  }
  __syncthreads();

  bf8_t qfh[4], qfl[4];
#pragma unroll
  for (int ks = 0; ks < 4; ++ks) {
    qfh[ks] = ld8(&qtH[l15][lh * 8 + ks * 32]);
    qfl[ks] = ld8(&qtL[l15][lh * 8 + ks * 32]);
  }
  float qtr[4], lq2[4];
#pragma unroll
  for (int r = 0; r < 4; ++r) {
    qtr[r] = qtS[lh * 4 + r];
    lq2[r] = 2.0f + lqS[lh * 4 + r];
  }
  float ktj[4], vtj[4], lvj[4];
#pragma unroll
  for (int n = 0; n < 4; ++n) {
    int j = j0 + n * 16 + l15;
    ktj[n] = kt[j]; vtj[n] = vt[j]; lvj[n] = lv[j];
  }

  auto loadT = [&](bf8_t* st, int nn) {
    size_t jrow = (size_t)(j0 + nn * 16 + l15) * 128 + lh * 8;
#pragma unroll
    for (int ks = 0; ks < 4; ++ks) {
      st[ks * 4 + 0] = ld8(Khi + jrow + ks * 32);
      st[ks * 4 + 1] = ld8(Klo + jrow + ks * 32);
      st[ks * 4 + 2] = ld8(Vhi + jrow + ks * 32);
      st[ks * 4 + 3] = ld8(Vlo + jrow + ks * 32);
    }
  };
  auto mfmaT = [&](const bf8_t* st, f32x4& s, f32x4& c) {
#pragma unroll
    for (int ks = 0; ks < 4; ++ks) {
      s = mfma16(qfh[ks], st[ks * 4 + 0], s);
      s = mfma16(qfh[ks], st[ks * 4 + 1], s);
      s = mfma16(qfl[ks], st[ks * 4 + 0], s);
      c = mfma16(qfh[ks], st[ks * 4 + 2], c);
      c = mfma16(qfh[ks], st[ks * 4 + 3], c);
      c = mfma16(qfl[ks], st[ks * 4 + 2], c);
    }
  };
  f32x4 sf[4], cf[4];
#pragma unroll
  for (int n = 0; n < 4; ++n) { sf[n] = f32x4{0, 0, 0, 0}; cf[n] = f32x4{0, 0, 0, 0}; }
  bf8_t stA[16], stB[16];
  loadT(stA, 0);
  loadT(stB, 1);
  mfmaT(stA, sf[0], cf[0]);
  loadT(stA, 2);
  mfmaT(stB, sf[1], cf[1]);
  loadT(stB, 3);
  mfmaT(stA, sf[2], cf[2]);
  mfmaT(stB, sf[3], cf[3]);

  bf8_t vA[16], vB[16];
  auto loadV = [&](bf8_t* st, int jk) {
#pragma unroll
    for (int dn = 0; dn < 8; ++dn) {
      size_t vrow = (size_t)(dn * 16 + l15) * 2048 + j0 + jk * 32 + lh * 8;
      st[dn * 2 + 0] = ld8(VThi + vrow);
      st[dn * 2 + 1] = ld8(VTlo + vrow);
    }
  };
  loadV(vA, 0);

  float lsum[4] = {0, 0, 0, 0}, tcs[4] = {0, 0, 0, 0}, tts[4] = {0, 0, 0, 0};
#pragma unroll
  for (int n = 0; n < 4; ++n) {
#pragma unroll
    for (int r = 0; r < 4; ++r) {
      float sim = sf[n][r] - qtr[r] * ktj[n];
      float c = cf[n][r] - qtr[r] * vtj[n];
      float e = expf(-BETA_F * sim);
      float z = fmaxf(-c, 1.0f + EPSF);
      float dist = acoshf(z);
      float den2 = fmaxf(lvj[n] + lq2[r] * c * c, EPSF);
      float g = e * dist * rsqrtf(den2);
      lsum[r] += e;
      tcs[r] += g * c;
      tts[r] += g * vtj[n];
      unsigned short gh = f2bf(g);
      unsigned short gl = f2bf(g - bf2f(gh));
      int q_ = lh * 4 + r;
      int idx = (q_ * 64 + n * 16 + l15) ^ ((q_ & 7) << 3);
      ghA[wv][idx] = gh;
      glA[wv][idx] = gl;
    }
  }
  loadV(vB, 1);
  asm volatile("s_waitcnt lgkmcnt(0)" ::: "memory");
  __builtin_amdgcn_sched_barrier(0);

  f32x4 accO[8];
#pragma unroll
  for (int dn = 0; dn < 8; ++dn) accO[dn] = f32x4{0, 0, 0, 0};
  {
    int base0 = (l15 * 64 + 0 * 32 + lh * 8) ^ ((l15 & 7) << 3);
    bf8_t ah = ld8(&ghA[wv][base0]);
    bf8_t al = ld8(&glA[wv][base0]);
#pragma unroll
    for (int dn = 0; dn < 8; ++dn) {
      accO[dn] = mfma16(ah, vA[dn * 2 + 0], accO[dn]);
      accO[dn] = mfma16(ah, vA[dn * 2 + 1], accO[dn]);
      accO[dn] = mfma16(al, vA[dn * 2 + 0], accO[dn]);
    }
  }
  {
    int base1 = (l15 * 64 + 1 * 32 + lh * 8) ^ ((l15 & 7) << 3);
    bf8_t ah = ld8(&ghA[wv][base1]);
    bf8_t al = ld8(&glA[wv][base1]);
#pragma unroll
    for (int dn = 0; dn < 8; ++dn) {
      accO[dn] = mfma16(ah, vB[dn * 2 + 0], accO[dn]);
      accO[dn] = mfma16(ah, vB[dn * 2 + 1], accO[dn]);
      accO[dn] = mfma16(al, vB[dn * 2 + 0], accO[dn]);
    }
  }

#pragma unroll
  for (int r = 0; r < 4; ++r) {
#pragma unroll
    for (int off = 1; off < 16; off <<= 1) {
      lsum[r] += __shfl_xor(lsum[r], off);
      tcs[r] += __shfl_xor(tcs[r], off);
      tts[r] += __shfl_xor(tts[r], off);
    }
  }

#pragma unroll
  for (int r = 0; r < 4; ++r) {
    int q_ = lh * 4 + r;
#pragma unroll
    for (int dn = 0; dn < 8; ++dn) mergeO[wv][q_][dn * 16 + l15] = accO[dn][r];
    if (l15 == 0) {
      mergeS[wv][0][q_] = lsum[r];
      mergeS[wv][1][q_] = tcs[r];
      mergeS[wv][2][q_] = tts[r];
    }
  }
  __syncthreads();

#pragma unroll
  for (int e = 0; e < 2; ++e) {
    int t = tid + e * 256;
    int q_ = t >> 5, d0 = (t & 31) * 4;
    float4 s = make_float4(0.f, 0.f, 0.f, 0.f);
#pragma unroll
    for (int w = 0; w < 4; ++w) {
      float4 v = *(const float4*)&mergeO[w][q_][d0];
      s.x += v.x; s.y += v.y; s.z += v.z; s.w += v.w;
    }
    float* P = part + ((size_t)(q0 + q_) * 8 + sp) * 132;
    *(float4*)(P + d0) = s;
  }
  if (tid < 16) {
    int q_ = tid;
    float a = 0, b = 0, cc2 = 0;
#pragma unroll
    for (int w = 0; w < 4; ++w) {
      a += mergeS[w][0][q_];
      b += mergeS[w][1][q_];
      cc2 += mergeS[w][2][q_];
    }
    float* P = part + ((size_t)(q0 + q_) * 8 + sp) * 132;
    P[128] = a; P[129] = b; P[130] = cc2;
  }
}

// ---------------- dispatch 3: merge + epilogue (recomputes Q from queries, FP chain identical) ----
__global__ void merge_fin(const float* __restrict__ part, const float* __restrict__ queries,
                          float* __restrict__ out) {
  int qi = blockIdx.x;
  int lane = threadIdx.x;  // 64
  const float* P = part + (size_t)qi * 8 * 132;
  float ox = 0, oy = 0, l = 0, tc = 0, tt = 0;
#pragma unroll
  for (int s = 0; s < 8; ++s) {
    const float* p = P + s * 132;
    float2 o2 = *(const float2*)(p + 2 * lane);
    ox += o2.x; oy += o2.y;
    l += p[128]; tc += p[129]; tt += p[130];
  }
  float2 rq = ((const float2*)(queries + (size_t)qi * 128))[lane];
  float s2q = wave_sum(rq.x * rq.x + rq.y * rq.y);
  float nq = sqrtf(s2q);
  float fq = fminf(3.5f / (nq + EPSF), 1.0f);
  float tq = fmaxf(nq * fq, EPSF);
  float coefq = sinhf(tq) / tq * fq;
  float qtv = coshf(tq);
  float qx = coefq * rq.x, qy = coefq * rq.y;   // == prep_q's Qs, bit-exact
  float invl = 1.0f / l;
  float Tmx = (ox + tc * qx) * invl;
  float Tmy = (oy + tc * qy) * invl;
  float Tmt = (tt + tc * qtv) * invl;
  float sp2 = wave_sum(Tmx * Tmx + Tmy * Tmy);
  float LT = sp2 - Tmt * Tmt;
  float un = sqrtf(fmaxf(LT, EPSF));
  float ch = coshf(un);
  float shv = sinhf(un) / un;
  float zx = ch * qx + shv * Tmx;
  float zy = ch * qy + shv * Tmy;
  float zt = ch * qtv + shv * Tmt;
  float zn2 = wave_sum(zx * zx + zy * zy);
  float nz = fmaxf(sqrtf(zn2), EPSF);
  float dist = acoshf(fmaxf(zt, 1.0f + EPSF));
  float sc = dist / nz;
  ((float2*)(out + (size_t)qi * 128))[lane] = make_float2(sc * zx, sc * zy);
}

extern "C" void kernel_launch(void* const* d_in, const int* in_sizes, int n_in,
                              void* d_out, int out_size, void* d_ws, size_t ws_size,
                              hipStream_t stream) {
  const float* queries = (const float*)d_in[0];
  const float* keys = (const float*)d_in[1];
  const float* values = (const float*)d_in[2];
  const float* WK = (const float*)d_in[3];
  const float* WV = (const float*)d_in[4];
  float* ws = (float*)d_ws;

  float* kt_ = ws + WS_KT;
  float* vt_ = ws + WS_VTM;
  float* lv_ = ws + WS_LV;
  unsigned short* Khi = (unsigned short*)(ws + WS_KHI);
  unsigned short* Klo = (unsigned short*)(ws + WS_KLO);
  unsigned short* Vhi = (unsigned short*)(ws + WS_VHI);
  unsigned short* Vlo = (unsigned short*)(ws + WS_VLO);
  unsigned short* VThi = (unsigned short*)(ws + WS_VTHI);
  unsigned short* VTlo = (unsigned short*)(ws + WS_VTLO);
  float* part = ws + WS_PART;
  float* out = (float*)d_out;

  prep_kv_w<<<256, 512, 0, stream>>>(keys, values, WK, WV,
                                     Khi, Klo, kt_, Vhi, Vlo, VThi, VTlo, vt_, lv_);
  attn_mfma<<<512, 256, 0, stream>>>(queries, Khi, Klo, Vhi, Vlo, VThi, VTlo,
                                     kt_, vt_, lv_, part);
  merge_fin<<<1024, 64, 0, stream>>>(part, queries, out);
}